// Round 4
// baseline (562.633 us; speedup 1.0000x reference)
//
#include <hip/hip_runtime.h>
#include <stdint.h>

typedef __bf16 bf16_t;
typedef bf16_t bf16x8 __attribute__((ext_vector_type(8)));
typedef float f32x4 __attribute__((ext_vector_type(4)));
typedef float f32x16 __attribute__((ext_vector_type(16)));
typedef unsigned uint32x2_t __attribute__((ext_vector_type(2)));
typedef unsigned uint32x4_t __attribute__((ext_vector_type(4)));

__device__ __forceinline__ unsigned short f2bf(float x) {
    unsigned u = __builtin_bit_cast(unsigned, x);
    u = (u + 0x7FFFu + ((u >> 16) & 1u)) >> 16;   // RNE
    return (unsigned short)u;
}

// pack two fp32 -> bf16x2 (round-half-up): 2 adds + 1 v_perm
__device__ __forceinline__ unsigned pk_bf16(float lo, float hi) {
    unsigned u0 = __builtin_bit_cast(unsigned, lo) + 0x8000u;
    unsigned u1 = __builtin_bit_cast(unsigned, hi) + 0x8000u;
    return __builtin_amdgcn_perm(u1, u0, 0x07060302u);
}

// CK-pattern async global->LDS, 16B per lane. LDS dest must be wave-uniform.
__device__ __forceinline__ void async_load16(const void* g, void* lds) {
    auto* gp = reinterpret_cast<const __attribute__((address_space(1))) uint32_t*>(
        reinterpret_cast<uintptr_t>(g));
    auto* lp = reinterpret_cast<__attribute__((address_space(3))) uint32_t*>(
        reinterpret_cast<uintptr_t>(lds));
    __builtin_amdgcn_global_load_lds(gp, lp, 16, 0, 0);
}

// ---------------- fused prep: casts + weight transposes in ONE launch ----------------
__device__ __forceinline__ void cast8(const float* __restrict__ src,
                                      unsigned short* __restrict__ dst, int i) {
    const float4* s4 = (const float4*)src;
    float4 a = s4[i * 2], b = s4[i * 2 + 1];
    uint4 o;
    o.x = (unsigned)f2bf(a.x) | ((unsigned)f2bf(a.y) << 16);
    o.y = (unsigned)f2bf(a.z) | ((unsigned)f2bf(a.w) << 16);
    o.z = (unsigned)f2bf(b.x) | ((unsigned)f2bf(b.y) << 16);
    o.w = (unsigned)f2bf(b.z) | ((unsigned)f2bf(b.w) << 16);
    ((uint4*)dst)[i] = o;
}

__device__ __forceinline__ void transcast_body(const float* __restrict__ src,
                                               unsigned short* __restrict__ dst,
                                               int K, int N, float scale,
                                               int bx, int by, float (*tile)[33],
                                               int x, int y) {
    int c0 = bx * 32, r0 = by * 32;
    #pragma unroll
    for (int i = 0; i < 32; i += 8)
        tile[y + i][x] = src[(size_t)(r0 + y + i) * N + c0 + x];
    __syncthreads();
    #pragma unroll
    for (int i = 0; i < 32; i += 8)
        dst[(size_t)(c0 + y + i) * K + r0 + x] = f2bf(tile[x][y + i] * scale);
}

// blocks: [0,4096) cast query; [4096,10240) cast context;
// [10240,11264) T(w_q); [11264,12800) T(w_kv); [12800,13824) T(w_out)
__global__ __launch_bounds__(256) void prep(const float* __restrict__ query,
                                            const float* __restrict__ context,
                                            const float* __restrict__ w_q,
                                            const float* __restrict__ w_kv,
                                            const float* __restrict__ w_out,
                                            unsigned short* __restrict__ qin,
                                            unsigned short* __restrict__ cin,
                                            unsigned short* __restrict__ wqT,
                                            unsigned short* __restrict__ wkvT,
                                            unsigned short* __restrict__ woutT,
                                            float qscale) {
    __shared__ float tile[32][33];
    const int blk = blockIdx.x, tid = threadIdx.x;
    const int x = tid & 31, y = tid >> 5;
    if (blk < 4096) {
        cast8(query, qin, blk * 256 + tid);
    } else if (blk < 10240) {
        cast8(context, cin, (blk - 4096) * 256 + tid);
    } else if (blk < 11264) {
        int lb = blk - 10240;
        transcast_body(w_q, wqT, 1024, 1024, qscale, lb & 31, lb >> 5, tile, x, y);
    } else if (blk < 12800) {
        int lb = blk - 11264;
        transcast_body(w_kv, wkvT, 768, 2048, 1.0f, lb & 63, lb >> 6, tile, x, y);
    } else {
        int lb = blk - 12800;
        transcast_body(w_out, woutT, 1024, 1024, 1.0f, lb & 31, lb >> 5, tile, x, y);
    }
}

// ---------------- C = A[M,K] * Bt[N,K]^T, bf16 MFMA, 128x128 tile, BK=64 ----------------
// Double-buffered LDS, prefetch-next-before-compute (T3 minimal 2-phase).
// EPI 0: bf16 out, stride N.  EPI 2: f32 out + bias.
template <int EPI>
__global__ __launch_bounds__(256) void gemm_bt(const unsigned short* __restrict__ A,
                                               const unsigned short* __restrict__ Bt,
                                               void* __restrict__ Cout,
                                               const float* __restrict__ bias,
                                               int K, int N, int nkt) {
    __shared__ __align__(16) unsigned short lA[2][128 * 64];  // 2 x 16 KB
    __shared__ __align__(16) unsigned short lB[2][128 * 64];  // 2 x 16 KB
    const int tid = threadIdx.x;
    const int w = tid >> 6, l = tid & 63;
    const int wm = w >> 1, wn = w & 1;
    const int row0 = blockIdx.y * 128, col0 = blockIdx.x * 128;
    const int lrow = l & 15, lq = l >> 4;
    const int srow = l >> 3;                 // 0..7: row within an issue's 8-row group
    const int scol = ((l & 7) ^ srow) * 8;   // XOR-swizzled k-chunk (elems)

    f32x4 acc[4][4];
    #pragma unroll
    for (int i = 0; i < 4; ++i)
        #pragma unroll
        for (int j = 0; j < 4; ++j) acc[i][j] = (f32x4)0.f;

    // hoisted per-q global source pointers; advance by 64 elems per staged tile
    const unsigned short* ga[4];
    const unsigned short* gb[4];
    #pragma unroll
    for (int q = 0; q < 4; ++q) {
        const int r = (w * 4 + q) * 8 + srow;
        ga[q] = A + (size_t)(row0 + r) * K + scol;
        gb[q] = Bt + (size_t)(col0 + r) * K + scol;
    }

    // prologue: stage kt=0 into buffer 0
    #pragma unroll
    for (int q = 0; q < 4; ++q) {
        async_load16(ga[q], (char*)lA + (w * 4 + q) * 1024);
        async_load16(gb[q], (char*)lB + (w * 4 + q) * 1024);
        ga[q] += 64;
        gb[q] += 64;
    }
    __syncthreads();

    for (int kt = 0; kt < nkt; ++kt) {
        const int bo = (kt & 1) * 16384;   // byte offset of current buffer
        if (kt + 1 < nkt) {
            const int bn = bo ^ 16384;
            #pragma unroll
            for (int q = 0; q < 4; ++q) {
                async_load16(ga[q], (char*)lA + bn + (w * 4 + q) * 1024);
                async_load16(gb[q], (char*)lB + bn + (w * 4 + q) * 1024);
                ga[q] += 64;
                gb[q] += 64;
            }
        }
        #pragma unroll
        for (int kc = 0; kc < 2; ++kc) {
            const int pc = ((kc * 4 + lq) ^ (lrow & 7)) * 16;  // byte offset of chunk
            bf16x8 af[4], bfr[4];
            #pragma unroll
            for (int i = 0; i < 4; ++i)
                af[i] = *(const bf16x8*)((const char*)lA + bo + (wm * 64 + i * 16 + lrow) * 128 + pc);
            #pragma unroll
            for (int j = 0; j < 4; ++j)
                bfr[j] = *(const bf16x8*)((const char*)lB + bo + (wn * 64 + j * 16 + lrow) * 128 + pc);
            #pragma unroll
            for (int i = 0; i < 4; ++i)
                #pragma unroll
                for (int j = 0; j < 4; ++j)
                    acc[i][j] = __builtin_amdgcn_mfma_f32_16x16x32_bf16(af[i], bfr[j],
                                                                        acc[i][j], 0, 0, 0);
        }
        __syncthreads();   // drains prefetch vmcnt; issued ~1 compute-phase earlier
    }
    #pragma unroll
    for (int i = 0; i < 4; ++i) {
        const int grow0 = row0 + wm * 64 + i * 16 + lq * 4;
        #pragma unroll
        for (int j = 0; j < 4; ++j) {
            const int gcol = col0 + wn * 64 + j * 16 + lrow;
            #pragma unroll
            for (int r = 0; r < 4; ++r) {
                float v = acc[i][j][r];
                int grow = grow0 + r;
                if (EPI == 0) {
                    ((unsigned short*)Cout)[(size_t)grow * N + gcol] = f2bf(v);
                } else {
                    ((float*)Cout)[(size_t)grow * N + gcol] = v + bias[gcol];
                }
            }
        }
    }
}

// ---------------- KV GEMM: 128x128 tile, 32x32x16 MFMA, wave tile 64x64, dbuf ----------------
// A = cin [16384 x 768], Bt = wkvT [2048 x 768], K=768 (12 BK=64 tiles).
// Double-buffered LDS (64 KB, 2 blocks/CU), prefetch-before-compute, 1 barrier/iter.
// cols<1024 -> Kb[b*2048+key][feat]; cols>=1024 -> Vt[(b*1024+fv)][key] packed dwordx2.
__global__ __launch_bounds__(256, 2) void gemm_kv(const unsigned short* __restrict__ A,
                                                  const unsigned short* __restrict__ Bt,
                                                  unsigned short* __restrict__ Kb,
                                                  unsigned short* __restrict__ Vt) {
    __shared__ __align__(16) unsigned short lA[2][128 * 64];  // 2 x 16 KB
    __shared__ __align__(16) unsigned short lB[2][128 * 64];  // 2 x 16 KB
    const int tid = threadIdx.x;
    const int w = tid >> 6, l = tid & 63;
    const int wm = w >> 1, wn = w & 1;
    const int row0 = blockIdx.y * 128, col0 = blockIdx.x * 128;
    const int r32 = l & 31, hw = l >> 5;
    const int srow = l >> 3, scol = ((l & 7) ^ srow) * 8;
    const int r7 = r32 & 7;

    f32x16 acc[2][2];
    #pragma unroll
    for (int mi = 0; mi < 2; ++mi)
        #pragma unroll
        for (int ni = 0; ni < 2; ++ni) acc[mi][ni] = (f32x16)0.f;

    const unsigned short* ga = A + (size_t)(row0 + w * 8 + srow) * 768 + scol;
    const unsigned short* gb = Bt + (size_t)(col0 + w * 8 + srow) * 768 + scol;
    const char* lap = (const char*)lA + (wm * 64 + r32) * 128;
    const char* lbp = (const char*)lB + (wn * 64 + r32) * 128;

    // prologue: stage kt=0 into buffer 0
    #pragma unroll
    for (int q = 0; q < 4; ++q) {
        async_load16(ga + (size_t)q * 32 * 768, (char*)lA + (q * 32 + w * 8) * 128);
        async_load16(gb + (size_t)q * 32 * 768, (char*)lB + (q * 32 + w * 8) * 128);
    }
    ga += 64;
    gb += 64;
    __syncthreads();

    for (int kt = 0; kt < 12; ++kt) {
        const int bo = (kt & 1) * 16384;
        if (kt < 11) {
            const int bn = bo ^ 16384;
            #pragma unroll
            for (int q = 0; q < 4; ++q) {
                async_load16(ga + (size_t)q * 32 * 768, (char*)lA + bn + (q * 32 + w * 8) * 128);
                async_load16(gb + (size_t)q * 32 * 768, (char*)lB + bn + (q * 32 + w * 8) * 128);
            }
            ga += 64;
            gb += 64;
        }
        #pragma unroll
        for (int ks = 0; ks < 4; ++ks) {
            const int off = ((ks * 2 + hw) ^ r7) * 16;  // byte offset of swizzled chunk
            bf16x8 af[2], bfr[2];
            #pragma unroll
            for (int mi = 0; mi < 2; ++mi)
                af[mi] = *(const bf16x8*)(lap + bo + mi * 32 * 128 + off);
            #pragma unroll
            for (int ni = 0; ni < 2; ++ni)
                bfr[ni] = *(const bf16x8*)(lbp + bo + ni * 32 * 128 + off);
            #pragma unroll
            for (int mi = 0; mi < 2; ++mi)
                #pragma unroll
                for (int ni = 0; ni < 2; ++ni)
                    acc[mi][ni] = __builtin_amdgcn_mfma_f32_32x32x16_bf16(af[mi], bfr[ni],
                                                                          acc[mi][ni], 0, 0, 0);
        }
        __syncthreads();
    }

    // C/D 32x32 layout: col = lane&31, row = (reg&3) + 8*(reg>>2) + 4*(lane>>5)
    if (col0 < 1024) {
        // K half: Kb[(row0 + wm*64 + rr) * 1024 + col0 + wn*64 + ni*32 + r32]
        unsigned short* kp = Kb + (size_t)(row0 + wm * 64) * 1024 + col0 + wn * 64 + r32;
        #pragma unroll
        for (int mi = 0; mi < 2; ++mi)
            #pragma unroll
            for (int ni = 0; ni < 2; ++ni)
                #pragma unroll
                for (int reg = 0; reg < 16; ++reg) {
                    int rr = mi * 32 + (reg & 3) + 8 * (reg >> 2) + 4 * hw;
                    kp[(size_t)rr * 1024 + ni * 32] = f2bf(acc[mi][ni][reg]);
                }
    } else {
        // V half: Vt[(b*1024 + fv)*2048 + key], 4 consecutive keys per dwordx2
        const int bb = row0 >> 11;
        const int keybase = (row0 & 2047) + wm * 64 + 4 * hw;
        const int fvbase = col0 - 1024 + wn * 64 + r32;
        unsigned short* vp = Vt + ((size_t)bb * 1024 + fvbase) * 2048 + keybase;
        #pragma unroll
        for (int mi = 0; mi < 2; ++mi)
            #pragma unroll
            for (int ni = 0; ni < 2; ++ni)
                #pragma unroll
                for (int g = 0; g < 4; ++g) {
                    uint2 pk2;
                    pk2.x = pk_bf16(acc[mi][ni][g * 4 + 0], acc[mi][ni][g * 4 + 1]);
                    pk2.y = pk_bf16(acc[mi][ni][g * 4 + 2], acc[mi][ni][g * 4 + 3]);
                    *(uint2*)(vp + (size_t)(ni * 32) * 2048 + mi * 32 + g * 8) = pk2;
                }
    }
}

// ---------------- flash attention, S^T formulation, no-max softmax ----------------
// 512-thread blocks: 128 q/block as 8 waves x one 16-q subtile. Grid (128 bh, 8 qtile)
// = 1024 blocks -> round-2 FETCH economics (8 qtile blocks per bh, ~86 MB), but
// 4 blocks/CU x 8 waves = up to 8 chains/SIMD (2x round 2) to cover the serial
// QK->exp->pack->permlane->PV chain. VGPR capped at 64 via launch_bounds(512,8).
// S^T = K @ Q^T, PV as O^T = V^T @ P^T; P^T via permlane32/16_swap in-register.
// l via ones-MFMA. K/V LDS double-buffered, prefetch-before-compute, 1 barrier/iter.
// Staging: each of 8 waves loads one 8-row group of K and of V (wave-uniform dest).
// Same-bh blocks share an XCD slot (x fastest, 128 % 8 == 0).
__global__ __launch_bounds__(512, 8) void attn_fwd(const unsigned short* __restrict__ qb,
                                                   const unsigned short* __restrict__ kb,
                                                   const unsigned short* __restrict__ vt,
                                                   unsigned short* __restrict__ ob) {
    __shared__ __align__(16) unsigned short lK[2][64 * 64];    // 2 x 8 KB, [key][d] XOR-swizzled
    __shared__ __align__(16) unsigned short lV[2][64 * 64];    // 2 x 8 KB, [d][key] XOR-swizzled
    const int tid = threadIdx.x;
    const int w = tid >> 6, l = tid & 63;
    const int bh = blockIdx.x;
    const int b = bh >> 4, h = bh & 15;
    const int q0 = blockIdx.y * 128;
    const int lrow = l & 15, lq = l >> 4;
    const int srow = l >> 3, scol = ((l & 7) ^ srow) * 8;

    // Q as MFMA B-operand: n=q=lrow, k=d=kc*32+lq*8+j ; 1 q-subtile per wave
    bf16x8 bq[2];
    #pragma unroll
    for (int kc = 0; kc < 2; ++kc) {
        int row = b * 1024 + q0 + w * 16 + lrow;
        int col = h * 64 + kc * 32 + lq * 8;
        bq[kc] = *(const bf16x8*)(qb + (size_t)row * 1024 + col);
    }

    f32x4 ot[4];               // O^T frags: q=lrow, d=16*dt+4*lq+r
    f32x4 lfr = (f32x4)0.f;    // l accumulator via ones-MFMA
    #pragma unroll
    for (int dt = 0; dt < 4; ++dt) ot[dt] = (f32x4)0.f;
    bf16x8 one8;
    #pragma unroll
    for (int i = 0; i < 8; ++i) one8[i] = (bf16_t)1.0f;

    // hoisted LDS fragment pointers (buffer 0; buffer 1 = +8192 B)
    const char* kp0 = (const char*)lK + lrow * 128 + ((lq ^ (lrow & 7)) * 16);
    const char* kp1 = (const char*)lK + lrow * 128 + (((4 + lq) ^ (lrow & 7)) * 16);
    const char* vp0 = (const char*)lV + lrow * 128 + ((lq ^ (lrow & 7)) * 16);
    const char* vp1 = (const char*)lV + lrow * 128 + (((4 + lq) ^ (lrow & 7)) * 16);

    // running global staging pointers: wave w owns rows w*8..w*8+7 of each tile
    const unsigned short* gkp = kb + (size_t)b * 2048 * 1024 + h * 64 +
                                (size_t)(w * 8 + srow) * 1024 + scol;
    const unsigned short* gvp = vt + ((size_t)(b * 1024 + h * 64 + w * 8 + srow)) * 2048 + scol;
    char* lKw = (char*)lK + (w * 8) * 128;
    char* lVw = (char*)lV + (w * 8) * 128;

    // prologue: stage it=0 into buffer 0
    async_load16(gkp, lKw);
    async_load16(gvp, lVw);
    gkp += 64 * 1024;
    gvp += 64;
    __syncthreads();

    for (int it = 0; it < 32; ++it) {
        const int bo = (it & 1) * 8192;   // byte offset of current buffer
        // prefetch next K/V tile into the other buffer (issued before compute)
        if (it < 31) {
            const int bn = bo ^ 8192;
            async_load16(gkp, lKw + bn);
            async_load16(gvp, lVw + bn);
            gkp += 64 * 1024;
            gvp += 64;
        }

        // K frags for this tile
        bf16x8 ka[4][2];
        #pragma unroll
        for (int mt = 0; mt < 4; ++mt) {
            ka[mt][0] = *(const bf16x8*)(kp0 + bo + mt * 2048);
            ka[mt][1] = *(const bf16x8*)(kp1 + bo + mt * 2048);
        }

        // S^T = K @ Q^T ; exp2 ; pack to dwords immediately (st transient)
        unsigned D[4][2];
        __builtin_amdgcn_s_setprio(1);
        #pragma unroll
        for (int mt = 0; mt < 4; ++mt) {
            f32x4 c = (f32x4)0.f;
            c = __builtin_amdgcn_mfma_f32_16x16x32_bf16(ka[mt][0], bq[0], c, 0, 0, 0);
            c = __builtin_amdgcn_mfma_f32_16x16x32_bf16(ka[mt][1], bq[1], c, 0, 0, 0);
            #pragma unroll
            for (int r = 0; r < 4; ++r)
                c[r] = __builtin_amdgcn_exp2f(c[r]);
            D[mt][0] = pk_bf16(c[0], c[1]);
            D[mt][1] = pk_bf16(c[2], c[3]);
        }
        __builtin_amdgcn_s_setprio(0);

        // in-register S^T -> P^T transpose within 4-lane groups {l, l+16, l+32, l+48}
        bf16x8 pb[2];   // [kcg]
        {
            uint32x4_t pbw[2];
            #pragma unroll
            for (int half = 0; half < 2; ++half) {   // half 0 -> mt{0,1} -> pb[0]; 1 -> mt{2,3} -> pb[1]
                #pragma unroll
                for (int r2 = 0; r2 < 2; ++r2) {
                    uint32x2_t t = __builtin_amdgcn_permlane32_swap(
                        D[half * 2][r2], D[half * 2 + 1][r2], false, false);
                    uint32x2_t z = __builtin_amdgcn_permlane16_swap(t.x, t.y, false, false);
                    pbw[half][r2] = z.x;        // slot j2 = r2
                    pbw[half][r2 + 2] = z.y;    // slot j2 = r2+2
                }
            }
            pb[0] = __builtin_bit_cast(bf16x8, pbw[0]);
            pb[1] = __builtin_bit_cast(bf16x8, pbw[1]);
        }

        // V frags (read after QK so ka regs are dead first)
        bf16x8 va[4][2];
        #pragma unroll
        for (int dt = 0; dt < 4; ++dt) {
            va[dt][0] = *(const bf16x8*)(vp0 + bo + dt * 2048);
            va[dt][1] = *(const bf16x8*)(vp1 + bo + dt * 2048);
        }

        // l += ones @ P^T (k-reduction inside MFMA), O^T += V^T @ P^T
        __builtin_amdgcn_s_setprio(1);
        lfr = __builtin_amdgcn_mfma_f32_16x16x32_bf16(one8, pb[0], lfr, 0, 0, 0);
        lfr = __builtin_amdgcn_mfma_f32_16x16x32_bf16(one8, pb[1], lfr, 0, 0, 0);
        #pragma unroll
        for (int dt = 0; dt < 4; ++dt) {
            ot[dt] = __builtin_amdgcn_mfma_f32_16x16x32_bf16(va[dt][0], pb[0], ot[dt], 0, 0, 0);
            ot[dt] = __builtin_amdgcn_mfma_f32_16x16x32_bf16(va[dt][1], pb[1], ot[dt], 0, 0, 0);
        }
        __builtin_amdgcn_s_setprio(0);
        __syncthreads();   // drains prefetch; all waves aligned for buffer swap
    }

    {
        float inv = 1.f / lfr[0];
        size_t grow = (size_t)(b * 1024 + q0 + w * 16 + lrow);
        unsigned short* op = ob + grow * 1024 + h * 64 + 4 * lq;
        #pragma unroll
        for (int dt = 0; dt < 4; ++dt) {
            uint2 pk;
            pk.x = pk_bf16(ot[dt][0] * inv, ot[dt][1] * inv);
            pk.y = pk_bf16(ot[dt][2] * inv, ot[dt][3] * inv);
            *(uint2*)(op + 16 * dt) = pk;
        }
    }
}

extern "C" void kernel_launch(void* const* d_in, const int* in_sizes, int n_in,
                              void* d_out, int out_size, void* d_ws, size_t ws_size,
                              hipStream_t stream) {
    const float* query   = (const float*)d_in[0];   // [8,1024,1024]
    const float* context = (const float*)d_in[1];   // [8,2048,768]
    const float* w_q     = (const float*)d_in[2];   // [1024,1024]
    const float* w_kv    = (const float*)d_in[3];   // [768,2048]
    const float* w_out   = (const float*)d_in[4];   // [1024,1024]
    const float* b_out   = (const float*)d_in[5];   // [1024]
    float* out = (float*)d_out;

    char* p = (char*)d_ws;
    unsigned short* qin   = (unsigned short*)p; p += (size_t)8192 * 1024 * 2;
    unsigned short* cin   = (unsigned short*)p; p += (size_t)16384 * 768 * 2;
    unsigned short* wqT   = (unsigned short*)p; p += (size_t)1024 * 1024 * 2;
    unsigned short* wkvT  = (unsigned short*)p; p += (size_t)2048 * 768 * 2;
    unsigned short* woutT = (unsigned short*)p; p += (size_t)1024 * 1024 * 2;
    unsigned short* qproj = (unsigned short*)p; p += (size_t)8192 * 1024 * 2;
    unsigned short* kbuf  = (unsigned short*)p; p += (size_t)16384 * 1024 * 2;
    unsigned short* vT    = (unsigned short*)p; p += (size_t)16384 * 1024 * 2;
    unsigned short* obuf  = (unsigned short*)p; p += (size_t)8192 * 1024 * 2;

    const float qscale = 0.125f * 1.44269504088896f;  // SCALE * log2(e), folded into w_q

    // fused prep: both input casts + all three weight transposes
    prep<<<13824, 256, 0, stream>>>(query, context, w_q, w_kv, w_out,
                                    qin, cin, wqT, wkvT, woutT, qscale);
    // q = (query @ w_q) * qscale
    gemm_bt<0><<<dim3(8, 64), 256, 0, stream>>>(qin, wqT, qproj, nullptr, 1024, 1024, 16);
    // kv = context @ w_kv -> kbuf (K) + vT (V transposed to [d][key])
    gemm_kv<<<dim3(16, 128), 256, 0, stream>>>(cin, wkvT, kbuf, vT);
    // attention: grid x = (b,h) for XCD-local K/V reuse, y = 128-row q tiles (8 waves)
    attn_fwd<<<dim3(128, 8), 512, 0, stream>>>(qproj, kbuf, vT, obuf);
    // out = o @ w_out + b_out
    gemm_bt<2><<<dim3(8, 64), 256, 0, stream>>>(obuf, woutT, out, b_out, 1024, 1024, 16);
}

// Round 5
// 330.814 us; speedup vs baseline: 1.7008x; 1.7008x over previous
//
#include <hip/hip_runtime.h>
#include <stdint.h>

typedef __bf16 bf16_t;
typedef bf16_t bf16x8 __attribute__((ext_vector_type(8)));
typedef float f32x4 __attribute__((ext_vector_type(4)));
typedef float f32x16 __attribute__((ext_vector_type(16)));
typedef unsigned uint32x2_t __attribute__((ext_vector_type(2)));
typedef unsigned uint32x4_t __attribute__((ext_vector_type(4)));

__device__ __forceinline__ unsigned short f2bf(float x) {
    unsigned u = __builtin_bit_cast(unsigned, x);
    u = (u + 0x7FFFu + ((u >> 16) & 1u)) >> 16;   // RNE
    return (unsigned short)u;
}

// pack two fp32 -> bf16x2 (round-half-up): 2 adds + 1 v_perm
__device__ __forceinline__ unsigned pk_bf16(float lo, float hi) {
    unsigned u0 = __builtin_bit_cast(unsigned, lo) + 0x8000u;
    unsigned u1 = __builtin_bit_cast(unsigned, hi) + 0x8000u;
    return __builtin_amdgcn_perm(u1, u0, 0x07060302u);
}

// CK-pattern async global->LDS, 16B per lane. LDS dest must be wave-uniform.
__device__ __forceinline__ void async_load16(const void* g, void* lds) {
    auto* gp = reinterpret_cast<const __attribute__((address_space(1))) uint32_t*>(
        reinterpret_cast<uintptr_t>(g));
    auto* lp = reinterpret_cast<__attribute__((address_space(3))) uint32_t*>(
        reinterpret_cast<uintptr_t>(lds));
    __builtin_amdgcn_global_load_lds(gp, lp, 16, 0, 0);
}

// ---------------- fused prep: casts + weight transposes in ONE launch ----------------
__device__ __forceinline__ void cast8(const float* __restrict__ src,
                                      unsigned short* __restrict__ dst, int i) {
    const float4* s4 = (const float4*)src;
    float4 a = s4[i * 2], b = s4[i * 2 + 1];
    uint4 o;
    o.x = (unsigned)f2bf(a.x) | ((unsigned)f2bf(a.y) << 16);
    o.y = (unsigned)f2bf(a.z) | ((unsigned)f2bf(a.w) << 16);
    o.z = (unsigned)f2bf(b.x) | ((unsigned)f2bf(b.y) << 16);
    o.w = (unsigned)f2bf(b.z) | ((unsigned)f2bf(b.w) << 16);
    ((uint4*)dst)[i] = o;
}

__device__ __forceinline__ void transcast_body(const float* __restrict__ src,
                                               unsigned short* __restrict__ dst,
                                               int K, int N, float scale,
                                               int bx, int by, float (*tile)[33],
                                               int x, int y) {
    int c0 = bx * 32, r0 = by * 32;
    #pragma unroll
    for (int i = 0; i < 32; i += 8)
        tile[y + i][x] = src[(size_t)(r0 + y + i) * N + c0 + x];
    __syncthreads();
    #pragma unroll
    for (int i = 0; i < 32; i += 8)
        dst[(size_t)(c0 + y + i) * K + r0 + x] = f2bf(tile[x][y + i] * scale);
}

// blocks: [0,4096) cast query; [4096,10240) cast context;
// [10240,11264) T(w_q); [11264,12800) T(w_kv); [12800,13824) T(w_out)
__global__ __launch_bounds__(256) void prep(const float* __restrict__ query,
                                            const float* __restrict__ context,
                                            const float* __restrict__ w_q,
                                            const float* __restrict__ w_kv,
                                            const float* __restrict__ w_out,
                                            unsigned short* __restrict__ qin,
                                            unsigned short* __restrict__ cin,
                                            unsigned short* __restrict__ wqT,
                                            unsigned short* __restrict__ wkvT,
                                            unsigned short* __restrict__ woutT,
                                            float qscale) {
    __shared__ float tile[32][33];
    const int blk = blockIdx.x, tid = threadIdx.x;
    const int x = tid & 31, y = tid >> 5;
    if (blk < 4096) {
        cast8(query, qin, blk * 256 + tid);
    } else if (blk < 10240) {
        cast8(context, cin, (blk - 4096) * 256 + tid);
    } else if (blk < 11264) {
        int lb = blk - 10240;
        transcast_body(w_q, wqT, 1024, 1024, qscale, lb & 31, lb >> 5, tile, x, y);
    } else if (blk < 12800) {
        int lb = blk - 11264;
        transcast_body(w_kv, wkvT, 768, 2048, 1.0f, lb & 63, lb >> 6, tile, x, y);
    } else {
        int lb = blk - 12800;
        transcast_body(w_out, woutT, 1024, 1024, 1.0f, lb & 31, lb >> 5, tile, x, y);
    }
}

// ---------------- C = A[M,K] * Bt[N,K]^T, bf16 MFMA, 128x128 tile, BK=64 ----------------
// Double-buffered LDS, prefetch-next-before-compute (T3 minimal 2-phase).
// EPI 0: bf16 out, stride N.  EPI 2: f32 out + bias.
template <int EPI>
__global__ __launch_bounds__(256) void gemm_bt(const unsigned short* __restrict__ A,
                                               const unsigned short* __restrict__ Bt,
                                               void* __restrict__ Cout,
                                               const float* __restrict__ bias,
                                               int K, int N, int nkt) {
    __shared__ __align__(16) unsigned short lA[2][128 * 64];  // 2 x 16 KB
    __shared__ __align__(16) unsigned short lB[2][128 * 64];  // 2 x 16 KB
    const int tid = threadIdx.x;
    const int w = tid >> 6, l = tid & 63;
    const int wm = w >> 1, wn = w & 1;
    const int row0 = blockIdx.y * 128, col0 = blockIdx.x * 128;
    const int lrow = l & 15, lq = l >> 4;
    const int srow = l >> 3;                 // 0..7: row within an issue's 8-row group
    const int scol = ((l & 7) ^ srow) * 8;   // XOR-swizzled k-chunk (elems)

    f32x4 acc[4][4];
    #pragma unroll
    for (int i = 0; i < 4; ++i)
        #pragma unroll
        for (int j = 0; j < 4; ++j) acc[i][j] = (f32x4)0.f;

    // hoisted per-q global source pointers; advance by 64 elems per staged tile
    const unsigned short* ga[4];
    const unsigned short* gb[4];
    #pragma unroll
    for (int q = 0; q < 4; ++q) {
        const int r = (w * 4 + q) * 8 + srow;
        ga[q] = A + (size_t)(row0 + r) * K + scol;
        gb[q] = Bt + (size_t)(col0 + r) * K + scol;
    }

    // prologue: stage kt=0 into buffer 0
    #pragma unroll
    for (int q = 0; q < 4; ++q) {
        async_load16(ga[q], (char*)lA + (w * 4 + q) * 1024);
        async_load16(gb[q], (char*)lB + (w * 4 + q) * 1024);
        ga[q] += 64;
        gb[q] += 64;
    }
    __syncthreads();

    for (int kt = 0; kt < nkt; ++kt) {
        const int bo = (kt & 1) * 16384;   // byte offset of current buffer
        if (kt + 1 < nkt) {
            const int bn = bo ^ 16384;
            #pragma unroll
            for (int q = 0; q < 4; ++q) {
                async_load16(ga[q], (char*)lA + bn + (w * 4 + q) * 1024);
                async_load16(gb[q], (char*)lB + bn + (w * 4 + q) * 1024);
                ga[q] += 64;
                gb[q] += 64;
            }
        }
        #pragma unroll
        for (int kc = 0; kc < 2; ++kc) {
            const int pc = ((kc * 4 + lq) ^ (lrow & 7)) * 16;  // byte offset of chunk
            bf16x8 af[4], bfr[4];
            #pragma unroll
            for (int i = 0; i < 4; ++i)
                af[i] = *(const bf16x8*)((const char*)lA + bo + (wm * 64 + i * 16 + lrow) * 128 + pc);
            #pragma unroll
            for (int j = 0; j < 4; ++j)
                bfr[j] = *(const bf16x8*)((const char*)lB + bo + (wn * 64 + j * 16 + lrow) * 128 + pc);
            #pragma unroll
            for (int i = 0; i < 4; ++i)
                #pragma unroll
                for (int j = 0; j < 4; ++j)
                    acc[i][j] = __builtin_amdgcn_mfma_f32_16x16x32_bf16(af[i], bfr[j],
                                                                        acc[i][j], 0, 0, 0);
        }
        __syncthreads();   // drains prefetch vmcnt; issued ~1 compute-phase earlier
    }
    #pragma unroll
    for (int i = 0; i < 4; ++i) {
        const int grow0 = row0 + wm * 64 + i * 16 + lq * 4;
        #pragma unroll
        for (int j = 0; j < 4; ++j) {
            const int gcol = col0 + wn * 64 + j * 16 + lrow;
            #pragma unroll
            for (int r = 0; r < 4; ++r) {
                float v = acc[i][j][r];
                int grow = grow0 + r;
                if (EPI == 0) {
                    ((unsigned short*)Cout)[(size_t)grow * N + gcol] = f2bf(v);
                } else {
                    ((float*)Cout)[(size_t)grow * N + gcol] = v + bias[gcol];
                }
            }
        }
    }
}

// ---------------- KV GEMM: 128x128 tile, 32x32x16 MFMA, wave tile 64x64, dbuf ----------------
// A = cin [16384 x 768], Bt = wkvT [2048 x 768], K=768 (12 BK=64 tiles).
// Double-buffered LDS (64 KB, 2 blocks/CU), prefetch-before-compute, 1 barrier/iter.
// cols<1024 -> Kb[b*2048+key][feat]; cols>=1024 -> Vt[(b*1024+fv)][key] packed dwordx2.
__global__ __launch_bounds__(256, 2) void gemm_kv(const unsigned short* __restrict__ A,
                                                  const unsigned short* __restrict__ Bt,
                                                  unsigned short* __restrict__ Kb,
                                                  unsigned short* __restrict__ Vt) {
    __shared__ __align__(16) unsigned short lA[2][128 * 64];  // 2 x 16 KB
    __shared__ __align__(16) unsigned short lB[2][128 * 64];  // 2 x 16 KB
    const int tid = threadIdx.x;
    const int w = tid >> 6, l = tid & 63;
    const int wm = w >> 1, wn = w & 1;
    const int row0 = blockIdx.y * 128, col0 = blockIdx.x * 128;
    const int r32 = l & 31, hw = l >> 5;
    const int srow = l >> 3, scol = ((l & 7) ^ srow) * 8;
    const int r7 = r32 & 7;

    f32x16 acc[2][2];
    #pragma unroll
    for (int mi = 0; mi < 2; ++mi)
        #pragma unroll
        for (int ni = 0; ni < 2; ++ni) acc[mi][ni] = (f32x16)0.f;

    const unsigned short* ga = A + (size_t)(row0 + w * 8 + srow) * 768 + scol;
    const unsigned short* gb = Bt + (size_t)(col0 + w * 8 + srow) * 768 + scol;
    const char* lap = (const char*)lA + (wm * 64 + r32) * 128;
    const char* lbp = (const char*)lB + (wn * 64 + r32) * 128;

    // prologue: stage kt=0 into buffer 0
    #pragma unroll
    for (int q = 0; q < 4; ++q) {
        async_load16(ga + (size_t)q * 32 * 768, (char*)lA + (q * 32 + w * 8) * 128);
        async_load16(gb + (size_t)q * 32 * 768, (char*)lB + (q * 32 + w * 8) * 128);
    }
    ga += 64;
    gb += 64;
    __syncthreads();

    for (int kt = 0; kt < 12; ++kt) {
        const int bo = (kt & 1) * 16384;
        if (kt < 11) {
            const int bn = bo ^ 16384;
            #pragma unroll
            for (int q = 0; q < 4; ++q) {
                async_load16(ga + (size_t)q * 32 * 768, (char*)lA + bn + (q * 32 + w * 8) * 128);
                async_load16(gb + (size_t)q * 32 * 768, (char*)lB + bn + (q * 32 + w * 8) * 128);
            }
            ga += 64;
            gb += 64;
        }
        #pragma unroll
        for (int ks = 0; ks < 4; ++ks) {
            const int off = ((ks * 2 + hw) ^ r7) * 16;  // byte offset of swizzled chunk
            bf16x8 af[2], bfr[2];
            #pragma unroll
            for (int mi = 0; mi < 2; ++mi)
                af[mi] = *(const bf16x8*)(lap + bo + mi * 32 * 128 + off);
            #pragma unroll
            for (int ni = 0; ni < 2; ++ni)
                bfr[ni] = *(const bf16x8*)(lbp + bo + ni * 32 * 128 + off);
            #pragma unroll
            for (int mi = 0; mi < 2; ++mi)
                #pragma unroll
                for (int ni = 0; ni < 2; ++ni)
                    acc[mi][ni] = __builtin_amdgcn_mfma_f32_32x32x16_bf16(af[mi], bfr[ni],
                                                                          acc[mi][ni], 0, 0, 0);
        }
        __syncthreads();
    }

    // C/D 32x32 layout: col = lane&31, row = (reg&3) + 8*(reg>>2) + 4*(lane>>5)
    if (col0 < 1024) {
        // K half: Kb[(row0 + wm*64 + rr) * 1024 + col0 + wn*64 + ni*32 + r32]
        unsigned short* kp = Kb + (size_t)(row0 + wm * 64) * 1024 + col0 + wn * 64 + r32;
        #pragma unroll
        for (int mi = 0; mi < 2; ++mi)
            #pragma unroll
            for (int ni = 0; ni < 2; ++ni)
                #pragma unroll
                for (int reg = 0; reg < 16; ++reg) {
                    int rr = mi * 32 + (reg & 3) + 8 * (reg >> 2) + 4 * hw;
                    kp[(size_t)rr * 1024 + ni * 32] = f2bf(acc[mi][ni][reg]);
                }
    } else {
        // V half: Vt[(b*1024 + fv)*2048 + key], 4 consecutive keys per dwordx2
        const int bb = row0 >> 11;
        const int keybase = (row0 & 2047) + wm * 64 + 4 * hw;
        const int fvbase = col0 - 1024 + wn * 64 + r32;
        unsigned short* vp = Vt + ((size_t)bb * 1024 + fvbase) * 2048 + keybase;
        #pragma unroll
        for (int mi = 0; mi < 2; ++mi)
            #pragma unroll
            for (int ni = 0; ni < 2; ++ni)
                #pragma unroll
                for (int g = 0; g < 4; ++g) {
                    uint2 pk2;
                    pk2.x = pk_bf16(acc[mi][ni][g * 4 + 0], acc[mi][ni][g * 4 + 1]);
                    pk2.y = pk_bf16(acc[mi][ni][g * 4 + 2], acc[mi][ni][g * 4 + 3]);
                    *(uint2*)(vp + (size_t)(ni * 32) * 2048 + mi * 32 + g * 8) = pk2;
                }
    }
}

// ---------------- flash attention, S^T formulation, no-max softmax ----------------
// 512-thread blocks: 128 q/block as 8 waves x one 16-q subtile. Grid (128 bh, 8 qtile)
// = 1024 blocks -> round-2 FETCH economics (~86 MB), with up to 8 chains/SIMD.
// launch_bounds(512, 4): round-4's (512,8) made hipcc cap VGPR at 32 -> massive
// scratch spill (WRITE_SIZE 540 MB, 3.3x regression). With the relaxed bound the
// natural allocation (~48-56 VGPR, cf. round 3's identical per-wave body at 48)
// stays <=64, so the HW still co-schedules 4 blocks/CU = 8 waves/SIMD -- occupancy
// comes from actual VGPR count, not the bound.
// S^T = K @ Q^T, PV as O^T = V^T @ P^T; P^T via permlane32/16_swap in-register.
// l via ones-MFMA. K/V LDS double-buffered, prefetch-before-compute, 1 barrier/iter.
// Staging: each of 8 waves loads one 8-row group of K and of V (wave-uniform dest).
// Same-bh blocks share an XCD slot (x fastest, 128 % 8 == 0).
__global__ __launch_bounds__(512, 4) void attn_fwd(const unsigned short* __restrict__ qb,
                                                   const unsigned short* __restrict__ kb,
                                                   const unsigned short* __restrict__ vt,
                                                   unsigned short* __restrict__ ob) {
    __shared__ __align__(16) unsigned short lK[2][64 * 64];    // 2 x 8 KB, [key][d] XOR-swizzled
    __shared__ __align__(16) unsigned short lV[2][64 * 64];    // 2 x 8 KB, [d][key] XOR-swizzled
    const int tid = threadIdx.x;
    const int w = tid >> 6, l = tid & 63;
    const int bh = blockIdx.x;
    const int b = bh >> 4, h = bh & 15;
    const int q0 = blockIdx.y * 128;
    const int lrow = l & 15, lq = l >> 4;
    const int srow = l >> 3, scol = ((l & 7) ^ srow) * 8;

    // Q as MFMA B-operand: n=q=lrow, k=d=kc*32+lq*8+j ; 1 q-subtile per wave
    bf16x8 bq[2];
    #pragma unroll
    for (int kc = 0; kc < 2; ++kc) {
        int row = b * 1024 + q0 + w * 16 + lrow;
        int col = h * 64 + kc * 32 + lq * 8;
        bq[kc] = *(const bf16x8*)(qb + (size_t)row * 1024 + col);
    }

    f32x4 ot[4];               // O^T frags: q=lrow, d=16*dt+4*lq+r
    f32x4 lfr = (f32x4)0.f;    // l accumulator via ones-MFMA
    #pragma unroll
    for (int dt = 0; dt < 4; ++dt) ot[dt] = (f32x4)0.f;
    bf16x8 one8;
    #pragma unroll
    for (int i = 0; i < 8; ++i) one8[i] = (bf16_t)1.0f;

    // hoisted LDS fragment pointers (buffer 0; buffer 1 = +8192 B)
    const char* kp0 = (const char*)lK + lrow * 128 + ((lq ^ (lrow & 7)) * 16);
    const char* kp1 = (const char*)lK + lrow * 128 + (((4 + lq) ^ (lrow & 7)) * 16);
    const char* vp0 = (const char*)lV + lrow * 128 + ((lq ^ (lrow & 7)) * 16);
    const char* vp1 = (const char*)lV + lrow * 128 + (((4 + lq) ^ (lrow & 7)) * 16);

    // running global staging pointers: wave w owns rows w*8..w*8+7 of each tile
    const unsigned short* gkp = kb + (size_t)b * 2048 * 1024 + h * 64 +
                                (size_t)(w * 8 + srow) * 1024 + scol;
    const unsigned short* gvp = vt + ((size_t)(b * 1024 + h * 64 + w * 8 + srow)) * 2048 + scol;
    char* lKw = (char*)lK + (w * 8) * 128;
    char* lVw = (char*)lV + (w * 8) * 128;

    // prologue: stage it=0 into buffer 0
    async_load16(gkp, lKw);
    async_load16(gvp, lVw);
    gkp += 64 * 1024;
    gvp += 64;
    __syncthreads();

    for (int it = 0; it < 32; ++it) {
        const int bo = (it & 1) * 8192;   // byte offset of current buffer
        // prefetch next K/V tile into the other buffer (issued before compute)
        if (it < 31) {
            const int bn = bo ^ 8192;
            async_load16(gkp, lKw + bn);
            async_load16(gvp, lVw + bn);
            gkp += 64 * 1024;
            gvp += 64;
        }

        // K frags for this tile
        bf16x8 ka[4][2];
        #pragma unroll
        for (int mt = 0; mt < 4; ++mt) {
            ka[mt][0] = *(const bf16x8*)(kp0 + bo + mt * 2048);
            ka[mt][1] = *(const bf16x8*)(kp1 + bo + mt * 2048);
        }

        // S^T = K @ Q^T ; exp2 ; pack to dwords immediately (st transient)
        unsigned D[4][2];
        __builtin_amdgcn_s_setprio(1);
        #pragma unroll
        for (int mt = 0; mt < 4; ++mt) {
            f32x4 c = (f32x4)0.f;
            c = __builtin_amdgcn_mfma_f32_16x16x32_bf16(ka[mt][0], bq[0], c, 0, 0, 0);
            c = __builtin_amdgcn_mfma_f32_16x16x32_bf16(ka[mt][1], bq[1], c, 0, 0, 0);
            #pragma unroll
            for (int r = 0; r < 4; ++r)
                c[r] = __builtin_amdgcn_exp2f(c[r]);
            D[mt][0] = pk_bf16(c[0], c[1]);
            D[mt][1] = pk_bf16(c[2], c[3]);
        }
        __builtin_amdgcn_s_setprio(0);

        // in-register S^T -> P^T transpose within 4-lane groups {l, l+16, l+32, l+48}
        bf16x8 pb[2];   // [kcg]
        {
            uint32x4_t pbw[2];
            #pragma unroll
            for (int half = 0; half < 2; ++half) {   // half 0 -> mt{0,1} -> pb[0]; 1 -> mt{2,3} -> pb[1]
                #pragma unroll
                for (int r2 = 0; r2 < 2; ++r2) {
                    uint32x2_t t = __builtin_amdgcn_permlane32_swap(
                        D[half * 2][r2], D[half * 2 + 1][r2], false, false);
                    uint32x2_t z = __builtin_amdgcn_permlane16_swap(t.x, t.y, false, false);
                    pbw[half][r2] = z.x;        // slot j2 = r2
                    pbw[half][r2 + 2] = z.y;    // slot j2 = r2+2
                }
            }
            pb[0] = __builtin_bit_cast(bf16x8, pbw[0]);
            pb[1] = __builtin_bit_cast(bf16x8, pbw[1]);
        }

        // V frags (read after QK so ka regs are dead first)
        bf16x8 va[4][2];
        #pragma unroll
        for (int dt = 0; dt < 4; ++dt) {
            va[dt][0] = *(const bf16x8*)(vp0 + bo + dt * 2048);
            va[dt][1] = *(const bf16x8*)(vp1 + bo + dt * 2048);
        }

        // l += ones @ P^T (k-reduction inside MFMA), O^T += V^T @ P^T
        __builtin_amdgcn_s_setprio(1);
        lfr = __builtin_amdgcn_mfma_f32_16x16x32_bf16(one8, pb[0], lfr, 0, 0, 0);
        lfr = __builtin_amdgcn_mfma_f32_16x16x32_bf16(one8, pb[1], lfr, 0, 0, 0);
        #pragma unroll
        for (int dt = 0; dt < 4; ++dt) {
            ot[dt] = __builtin_amdgcn_mfma_f32_16x16x32_bf16(va[dt][0], pb[0], ot[dt], 0, 0, 0);
            ot[dt] = __builtin_amdgcn_mfma_f32_16x16x32_bf16(va[dt][1], pb[1], ot[dt], 0, 0, 0);
        }
        __builtin_amdgcn_s_setprio(0);
        __syncthreads();   // drains prefetch; all waves aligned for buffer swap
    }

    {
        float inv = 1.f / lfr[0];
        size_t grow = (size_t)(b * 1024 + q0 + w * 16 + lrow);
        unsigned short* op = ob + grow * 1024 + h * 64 + 4 * lq;
        #pragma unroll
        for (int dt = 0; dt < 4; ++dt) {
            uint2 pk;
            pk.x = pk_bf16(ot[dt][0] * inv, ot[dt][1] * inv);
            pk.y = pk_bf16(ot[dt][2] * inv, ot[dt][3] * inv);
            *(uint2*)(op + 16 * dt) = pk;
        }
    }
}

extern "C" void kernel_launch(void* const* d_in, const int* in_sizes, int n_in,
                              void* d_out, int out_size, void* d_ws, size_t ws_size,
                              hipStream_t stream) {
    const float* query   = (const float*)d_in[0];   // [8,1024,1024]
    const float* context = (const float*)d_in[1];   // [8,2048,768]
    const float* w_q     = (const float*)d_in[2];   // [1024,1024]
    const float* w_kv    = (const float*)d_in[3];   // [768,2048]
    const float* w_out   = (const float*)d_in[4];   // [1024,1024]
    const float* b_out   = (const float*)d_in[5];   // [1024]
    float* out = (float*)d_out;

    char* p = (char*)d_ws;
    unsigned short* qin   = (unsigned short*)p; p += (size_t)8192 * 1024 * 2;
    unsigned short* cin   = (unsigned short*)p; p += (size_t)16384 * 768 * 2;
    unsigned short* wqT   = (unsigned short*)p; p += (size_t)1024 * 1024 * 2;
    unsigned short* wkvT  = (unsigned short*)p; p += (size_t)2048 * 768 * 2;
    unsigned short* woutT = (unsigned short*)p; p += (size_t)1024 * 1024 * 2;
    unsigned short* qproj = (unsigned short*)p; p += (size_t)8192 * 1024 * 2;
    unsigned short* kbuf  = (unsigned short*)p; p += (size_t)16384 * 1024 * 2;
    unsigned short* vT    = (unsigned short*)p; p += (size_t)16384 * 1024 * 2;
    unsigned short* obuf  = (unsigned short*)p; p += (size_t)8192 * 1024 * 2;

    const float qscale = 0.125f * 1.44269504088896f;  // SCALE * log2(e), folded into w_q

    // fused prep: both input casts + all three weight transposes
    prep<<<13824, 256, 0, stream>>>(query, context, w_q, w_kv, w_out,
                                    qin, cin, wqT, wkvT, woutT, qscale);
    // q = (query @ w_q) * qscale
    gemm_bt<0><<<dim3(8, 64), 256, 0, stream>>>(qin, wqT, qproj, nullptr, 1024, 1024, 16);
    // kv = context @ w_kv -> kbuf (K) + vT (V transposed to [d][key])
    gemm_kv<<<dim3(16, 128), 256, 0, stream>>>(cin, wkvT, kbuf, vT);
    // attention: grid x = (b,h) for XCD-local K/V reuse, y = 128-row q tiles (8 waves)
    attn_fwd<<<dim3(128, 8), 512, 0, stream>>>(qproj, kbuf, vT, obuf);
    // out = o @ w_out + b_out
    gemm_bt<2><<<dim3(8, 64), 256, 0, stream>>>(obuf, woutT, out, b_out, 1024, 1024, 16);
}